// Round 6
// baseline (275.707 us; speedup 1.0000x reference)
//
#include <hip/hip_runtime.h>

#define DEV __device__ __forceinline__

typedef __attribute__((ext_vector_type(8))) short bf16x8;
typedef __attribute__((ext_vector_type(4))) float f32x4;

constexpr int Nn = 4096, Dd = 256, Kk = 128;
constexpr int RT = 128;     // rows per row-tile
constexpr int TILES = 4;    // row-tiles per block (512 rows)
constexpr int CHUNKS = 8;   // blocks per batch; grid = 32*8 = 256

DEV unsigned short f2bf(float f) {
  unsigned int u = __builtin_bit_cast(unsigned int, f);
  u += 0x7FFFu + ((u >> 16) & 1u);          // RNE; inputs are finite
  return (unsigned short)(u >> 16);
}
DEV float bf2f(unsigned short h) {
  unsigned int u = (unsigned int)h << 16;
  return __builtin_bit_cast(float, u);
}

// 256B LDS rows (128 bf16). XOR-swizzle bits 4-6 by h(row)=(row&7)^(((row>>3)&3)<<1):
// scalar b16 scatter writes and b128 fragment reads both stay <=2-way (free).
// h(row+32)==h(row), so xT store addresses are invariant under +32-row steps.
DEV unsigned lds_addr(unsigned row, unsigned byteInRow) {
  unsigned h = (row & 7u) ^ (((row >> 3) & 3u) << 1);
  return row * 256u + (byteInRow ^ (h << 4));
}

__global__ void enc_prep(const float* __restrict__ cw, const float* __restrict__ sc,
                         unsigned short* __restrict__ cbf, float2* __restrict__ tab) {
  int k = blockIdx.x, l = threadIdx.x;          // 128 blocks x 64 threads
  float4 u = *(const float4*)(cw + k * Dd + l * 4);
  float s2 = u.x * u.x + u.y * u.y + u.z * u.z + u.w * u.w;
  #pragma unroll
  for (int o = 1; o < 64; o <<= 1) s2 += __shfl_xor(s2, o);
  unsigned short* dst = cbf + k * Dd + l * 4;
  dst[0] = f2bf(u.x); dst[1] = f2bf(u.y); dst[2] = f2bf(u.z); dst[3] = f2bf(u.w);
  if (l == 0) { float s = sc[k]; tab[k] = make_float2(s * s2, 2.0f * s); }
}

// PMODE: 0 = fp32 partials to Ep, 1 = bf16 partials to Ep, 2 = atomicAdd to out
template<int PMODE>
DEV void enc_impl(const float* __restrict__ x, const unsigned short* __restrict__ cbf,
                  const float2* __restrict__ tab, const float* __restrict__ cwf,
                  char* __restrict__ Ep, float* __restrict__ out) {
  // LDS: xT (256 x 128 bf16, swz) = 64KB ; W (128 x 128 bf16, swz) = 32KB ; misc 1.5KB
  __shared__ __align__(16) char smem[98304];
  __shared__ float WsumL[Kk];
  __shared__ float2 tabL[Kk];
  char* Wb = smem + 65536;

  const int tid = threadIdx.x;
  const int w  = tid >> 6;           // wave 0..7
  const int l  = tid & 63;
  const int g  = l >> 4;             // 16-lane group 0..3
  const int ln = l & 15;
  const int wr = w >> 2, wc = w & 3; // phase-2 wave grid 2x4 over E(128 x 256)
  const int b = blockIdx.x >> 3, chunk = blockIdx.x & 7;
  const int row = w * 16 + ln;       // this lane's n-row within the tile

  const float* xb = x + ((size_t)b * Nn + (size_t)chunk * (TILES * RT)) * Dd;

  // Warm tile 0 into L2: 512 thr x 4 touches x 64B lines = 128KB = one tile.
  {
    const size_t lid = (size_t)tid * 4;
    float t0 = xb[(lid + 0) * 16], t1 = xb[(lid + 1) * 16];
    float t2 = xb[(lid + 2) * 16], t3 = xb[(lid + 3) * 16];
    asm volatile("" :: "v"(t0), "v"(t1), "v"(t2), "v"(t3));
  }

  if (tid < Kk) { WsumL[tid] = 0.0f; tabL[tid] = tab[tid]; }
  __syncthreads();

  f32x4 acc[4][4];
  const f32x4 zero4 = {0.f, 0.f, 0.f, 0.f};
  #pragma unroll
  for (int mi = 0; mi < 4; ++mi)
    #pragma unroll
    for (int ni = 0; ni < 4; ++ni) acc[mi][ni] = zero4;

  const unsigned colb = (unsigned)row * 2u;  // this lane's n-column (bytes)
  // hoisted xT store addresses (rows g*8+i); +ks*8192 folds into the offset imm
  unsigned a_st[8];
  #pragma unroll
  for (int i = 0; i < 8; ++i) a_st[i] = lds_addr((unsigned)(g * 8 + i), colb);

  for (int t = 0; t < TILES; ++t) {
    // ---- software prefetch: touch every 64B line of tile t+1 (fire-and-forget;
    // the asm-keep at the tile's end forces liveness without an early stall).
    const int tn = (t + 1 < TILES) ? t + 1 : t;
    const float* tnb = xb + (size_t)tn * RT * Dd;
    const size_t lid = (size_t)tid * 4;
    float p0 = tnb[(lid + 0) * 16], p1 = tnb[(lid + 1) * 16];
    float p2 = tnb[(lid + 2) * 16], p3 = tnb[(lid + 3) * 16];

    // -------- Phase 1: S^T = mfma(c, x); each wave owns 16 rows x all 128 cw
    const float* xrow = xb + ((size_t)t * RT + row) * Dd;
    f32x4 s1[8];
    #pragma unroll
    for (int f = 0; f < 8; ++f) s1[f] = zero4;
    float x2p = 0.f;

    #pragma unroll
    for (int ks = 0; ks < 8; ++ks) {
      const int d0 = ks * 32 + g * 8;
      float4 u0 = *(const float4*)(xrow + d0);
      float4 u1 = *(const float4*)(xrow + d0 + 4);
      x2p += u0.x*u0.x + u0.y*u0.y + u0.z*u0.z + u0.w*u0.w
           + u1.x*u1.x + u1.y*u1.y + u1.z*u1.z + u1.w*u1.w;
      unsigned short q0 = f2bf(u0.x), q1 = f2bf(u0.y), q2 = f2bf(u0.z), q3 = f2bf(u0.w);
      unsigned short q4 = f2bf(u1.x), q5 = f2bf(u1.y), q6 = f2bf(u1.z), q7 = f2bf(u1.w);
      bf16x8 xv;
      xv[0] = (short)q0; xv[1] = (short)q1; xv[2] = (short)q2; xv[3] = (short)q3;
      xv[4] = (short)q4; xv[5] = (short)q5; xv[6] = (short)q6; xv[7] = (short)q7;
      // single x read feeds both MFMA operand and transposed LDS stage
      *(unsigned short*)(smem + a_st[0] + ks * 8192) = q0;
      *(unsigned short*)(smem + a_st[1] + ks * 8192) = q1;
      *(unsigned short*)(smem + a_st[2] + ks * 8192) = q2;
      *(unsigned short*)(smem + a_st[3] + ks * 8192) = q3;
      *(unsigned short*)(smem + a_st[4] + ks * 8192) = q4;
      *(unsigned short*)(smem + a_st[5] + ks * 8192) = q5;
      *(unsigned short*)(smem + a_st[6] + ks * 8192) = q6;
      *(unsigned short*)(smem + a_st[7] + ks * 8192) = q7;
      #pragma unroll
      for (int f = 0; f < 8; ++f) {
        bf16x8 a = *(const bf16x8*)(cbf + (f * 16 + ln) * Dd + d0);
        s1[f] = __builtin_amdgcn_mfma_f32_16x16x32_bf16(a, xv, s1[f], 0, 0, 0);
      }
    }

    // -------- softmax over K (lane-local: 32 values + 2 shuffles)
    x2p += __shfl_xor(x2p, 16); x2p += __shfl_xor(x2p, 32);
    const float hx2 = 0.5f * x2p;
    float ssum = 0.f;
    #pragma unroll
    for (int f = 0; f < 8; ++f) {
      #pragma unroll
      for (int r = 0; r < 4; ++r) {
        const float2 ab = tabL[f * 16 + g * 4 + r];     // (alpha, beta)
        const float ev = __expf(ab.x + ab.y * (hx2 - s1[f][r]));
        s1[f][r] = ev;
        ssum += ev;
      }
    }
    ssum += __shfl_xor(ssum, 16); ssum += __shfl_xor(ssum, 32);
    const float rinv = 1.0f / ssum;

    #pragma unroll
    for (int f = 0; f < 8; ++f) {
      #pragma unroll
      for (int r = 0; r < 4; ++r) {
        const int cwi = f * 16 + g * 4 + r;
        const float wv = s1[f][r] * rinv;
        *(unsigned short*)(Wb + lds_addr((unsigned)cwi, colb)) = f2bf(wv);
        float tsum = wv;                                // sum over the wave's 16 rows
        tsum += __shfl_xor(tsum, 1);
        tsum += __shfl_xor(tsum, 2);
        tsum += __shfl_xor(tsum, 4);
        tsum += __shfl_xor(tsum, 8);
        if (ln == 0) atomicAdd(&WsumL[cwi], tsum);
      }
    }
    __syncthreads();   // xT + W complete

    // -------- Phase 2: E(128x256) += W^T-frags x xT-frags, 2x4 wave grid
    #pragma unroll
    for (int ks2 = 0; ks2 < 4; ++ks2) {
      const unsigned nb = (unsigned)(ks2 * 32 + g * 8) * 2u;
      bf16x8 af[4], bg[4];
      #pragma unroll
      for (int mi = 0; mi < 4; ++mi)
        af[mi] = *(const bf16x8*)(Wb + lds_addr((unsigned)(wr * 64 + mi * 16 + ln), nb));
      #pragma unroll
      for (int ni = 0; ni < 4; ++ni)
        bg[ni] = *(const bf16x8*)(smem + lds_addr((unsigned)(wc * 64 + ni * 16 + ln), nb));
      #pragma unroll
      for (int mi = 0; mi < 4; ++mi)
        #pragma unroll
        for (int ni = 0; ni < 4; ++ni)
          acc[mi][ni] = __builtin_amdgcn_mfma_f32_16x16x32_bf16(af[mi], bg[ni], acc[mi][ni], 0, 0, 0);
    }

    // keep the touch loads live (waitcnt lands here, ~a full tile after issue)
    asm volatile("" :: "v"(p0), "v"(p1), "v"(p2), "v"(p3));
    __syncthreads();   // before next tile overwrites xT/W
  }

  // -------- epilogue: Epart[k,d] = acc - Wsum_chunk * c
  #pragma unroll
  for (int mi = 0; mi < 4; ++mi) {
    #pragma unroll
    for (int r = 0; r < 4; ++r) {
      const int cwi = wr * 64 + mi * 16 + g * 4 + r;
      const float wsv = WsumL[cwi];
      #pragma unroll
      for (int ni = 0; ni < 4; ++ni) {
        const int d = wc * 64 + ni * 16 + ln;
        const float v = acc[mi][ni][r] - wsv * cwf[cwi * Dd + d];
        if (PMODE == 0) {
          ((float*)Ep)[(size_t)blockIdx.x * (Kk * Dd) + cwi * Dd + d] = v;
        } else if (PMODE == 1) {
          ((unsigned short*)Ep)[(size_t)blockIdx.x * (Kk * Dd) + cwi * Dd + d] = f2bf(v);
        } else {
          atomicAdd(out + (size_t)b * (Kk * Dd) + cwi * Dd + d, v);
        }
      }
    }
  }
}

// 2nd launch_bounds arg behaves as min BLOCKS/CU here (VGPR cap = 2048/(waves/CU));
// (512,1) -> 256-VGPR budget, kernel fits without spill.
__global__ __launch_bounds__(512, 1) void enc_main_f32(
    const float* __restrict__ x, const unsigned short* __restrict__ cbf,
    const float2* __restrict__ tab, const float* __restrict__ cwf,
    char* __restrict__ Ep, float* __restrict__ out) {
  enc_impl<0>(x, cbf, tab, cwf, Ep, out);
}
__global__ __launch_bounds__(512, 1) void enc_main_b16(
    const float* __restrict__ x, const unsigned short* __restrict__ cbf,
    const float2* __restrict__ tab, const float* __restrict__ cwf,
    char* __restrict__ Ep, float* __restrict__ out) {
  enc_impl<1>(x, cbf, tab, cwf, Ep, out);
}
__global__ __launch_bounds__(512, 1) void enc_main_atm(
    const float* __restrict__ x, const unsigned short* __restrict__ cbf,
    const float2* __restrict__ tab, const float* __restrict__ cwf,
    char* __restrict__ Ep, float* __restrict__ out) {
  enc_impl<2>(x, cbf, tab, cwf, nullptr, out);
}

// Each thread reduces 16 consecutive floats over 8 chunks: 32 independent
// 16B loads in flight per lane (in-flight-bytes bound, not BW bound).
__global__ __launch_bounds__(256, 1) void enc_reduce_f32(
    const float* __restrict__ Ep, float* __restrict__ out) {
  const size_t i = ((size_t)blockIdx.x * 256 + threadIdx.x) * 16;
  const int b   = (int)(i / (Kk * Dd));
  const int rem = (int)(i % (Kk * Dd));
  const float* p = Ep + (size_t)b * CHUNKS * (Kk * Dd) + rem;
  float sx[16];
  #pragma unroll
  for (int j = 0; j < 16; ++j) sx[j] = 0.f;
  #pragma unroll
  for (int c = 0; c < CHUNKS; ++c) {
    const float4* q = (const float4*)(p + (size_t)c * (Kk * Dd));
    float4 v0 = q[0], v1 = q[1], v2 = q[2], v3 = q[3];
    sx[0] += v0.x; sx[1] += v0.y; sx[2]  += v0.z; sx[3]  += v0.w;
    sx[4] += v1.x; sx[5] += v1.y; sx[6]  += v1.z; sx[7]  += v1.w;
    sx[8] += v2.x; sx[9] += v2.y; sx[10] += v2.z; sx[11] += v2.w;
    sx[12] += v3.x; sx[13] += v3.y; sx[14] += v3.z; sx[15] += v3.w;
  }
  float4* o = (float4*)(out + i);
  o[0] = make_float4(sx[0], sx[1], sx[2], sx[3]);
  o[1] = make_float4(sx[4], sx[5], sx[6], sx[7]);
  o[2] = make_float4(sx[8], sx[9], sx[10], sx[11]);
  o[3] = make_float4(sx[12], sx[13], sx[14], sx[15]);
}

__global__ void enc_reduce_bf16(const unsigned short* __restrict__ Ep, float* __restrict__ out) {
  const size_t i = ((size_t)blockIdx.x * 256 + threadIdx.x) * 4;
  const int b   = (int)(i / (Kk * Dd));
  const int rem = (int)(i % (Kk * Dd));
  const unsigned short* p = Ep + (size_t)b * CHUNKS * (Kk * Dd) + rem;
  float sx = 0.f, sy = 0.f, sz = 0.f, sw = 0.f;
  #pragma unroll
  for (int c = 0; c < CHUNKS; ++c) {
    ushort4 v = *(const ushort4*)(p + (size_t)c * (Kk * Dd));
    sx += bf2f(v.x); sy += bf2f(v.y); sz += bf2f(v.z); sw += bf2f(v.w);
  }
  float4 s = make_float4(sx, sy, sz, sw);
  *(float4*)(out + i) = s;
}

extern "C" void kernel_launch(void* const* d_in, const int* in_sizes, int n_in,
                              void* d_out, int out_size, void* d_ws, size_t ws_size,
                              hipStream_t stream) {
  const float* x  = (const float*)d_in[0];   // (32, 4096, 256)
  const float* cw = (const float*)d_in[1];   // (128, 256)
  const float* sc = (const float*)d_in[2];   // (128,)
  float* out = (float*)d_out;                // (32, 128, 256)

  unsigned short* cbf = (unsigned short*)d_ws;                    // 64KB bf16 codewords
  float2* tab = (float2*)((char*)d_ws + 65536);                   // 1KB (alpha, beta)
  char*   Ep  = (char*)d_ws + 66560;                              // chunk partials
  const size_t KD = (size_t)Kk * Dd;
  const size_t needF32 = 66560 + (size_t)32 * CHUNKS * KD * 4;    // ~33.6 MB
  const size_t needB16 = 66560 + (size_t)32 * CHUNKS * KD * 2;    // ~16.8 MB

  enc_prep<<<dim3(Kk), dim3(64), 0, stream>>>(cw, sc, cbf, tab);

  if (ws_size >= needF32) {
    enc_main_f32<<<dim3(256), dim3(512), 0, stream>>>(x, cbf, tab, cw, Ep, out);
    const int rgrid = (int)((32 * KD) / (256 * 16));              // 256 blocks
    enc_reduce_f32<<<dim3(rgrid), dim3(256), 0, stream>>>((const float*)Ep, out);
  } else if (ws_size >= needB16) {
    enc_main_b16<<<dim3(256), dim3(512), 0, stream>>>(x, cbf, tab, cw, Ep, out);
    const int rgrid = (int)((32 * KD) / (256 * 4));               // 1024 blocks
    enc_reduce_bf16<<<dim3(rgrid), dim3(256), 0, stream>>>((const unsigned short*)Ep, out);
  } else {
    hipMemsetAsync(d_out, 0, (size_t)out_size * sizeof(float), stream);
    enc_main_atm<<<dim3(256), dim3(512), 0, stream>>>(x, cbf, tab, cw, nullptr, out);
  }
}

// Round 7
// 208.175 us; speedup vs baseline: 1.3244x; 1.3244x over previous
//
#include <hip/hip_runtime.h>

#define DEV __device__ __forceinline__

typedef __attribute__((ext_vector_type(8))) short bf16x8;
typedef __attribute__((ext_vector_type(4))) float f32x4;

constexpr int Nn = 4096, Dd = 256, Kk = 128;
constexpr int RT = 128;     // rows per row-tile
constexpr int TILES = 4;    // row-tiles per block (512 rows)
constexpr int CHUNKS = 8;   // blocks per batch; grid = 32*8 = 256

DEV unsigned short f2bf(float f) {
  unsigned int u = __builtin_bit_cast(unsigned int, f);
  u += 0x7FFFu + ((u >> 16) & 1u);          // RNE; inputs are finite
  return (unsigned short)(u >> 16);
}
DEV float bf2f(unsigned short h) {
  unsigned int u = (unsigned int)h << 16;
  return __builtin_bit_cast(float, u);
}

// 256B LDS rows (128 bf16). XOR-swizzle bits 4-6 by h(row)=(row&7)^(((row>>3)&3)<<1):
// scalar b16 scatter writes and b128 fragment reads both stay <=2-way (free).
// h(row+32)==h(row), so xT store addresses are invariant under +32-row steps.
DEV unsigned lds_addr(unsigned row, unsigned byteInRow) {
  unsigned h = (row & 7u) ^ (((row >> 3) & 3u) << 1);
  return row * 256u + (byteInRow ^ (h << 4));
}

__global__ void enc_prep(const float* __restrict__ cw, const float* __restrict__ sc,
                         unsigned short* __restrict__ cbf, float2* __restrict__ tab) {
  int k = blockIdx.x, l = threadIdx.x;          // 128 blocks x 64 threads
  float4 u = *(const float4*)(cw + k * Dd + l * 4);
  float s2 = u.x * u.x + u.y * u.y + u.z * u.z + u.w * u.w;
  #pragma unroll
  for (int o = 1; o < 64; o <<= 1) s2 += __shfl_xor(s2, o);
  unsigned short* dst = cbf + k * Dd + l * 4;
  dst[0] = f2bf(u.x); dst[1] = f2bf(u.y); dst[2] = f2bf(u.z); dst[3] = f2bf(u.w);
  if (l == 0) { float s = sc[k]; tab[k] = make_float2(s * s2, 2.0f * s); }
}

// PMODE: 0 = fp32 partials to Ep, 1 = bf16 partials to Ep, 2 = atomicAdd to out
template<int PMODE>
DEV void enc_impl(const float* __restrict__ x, const unsigned short* __restrict__ cbf,
                  const float2* __restrict__ tab, const float* __restrict__ cwf,
                  char* __restrict__ Ep, float* __restrict__ out) {
  // LDS: xT (256 x 128 bf16, swz) = 64KB ; W (128 x 128 bf16, swz) = 32KB ; misc 1.5KB
  __shared__ __align__(16) char smem[98304];
  __shared__ float WsumL[Kk];
  __shared__ float2 tabL[Kk];
  char* Wb = smem + 65536;

  const int tid = threadIdx.x;
  const int w  = tid >> 6;           // wave 0..7
  const int l  = tid & 63;
  const int g  = l >> 4;             // 16-lane group 0..3
  const int ln = l & 15;
  const int wr = w >> 2, wc = w & 3; // phase-2 wave grid 2x4 over E(128 x 256)
  const int b = blockIdx.x >> 3, chunk = blockIdx.x & 7;
  const int row = w * 16 + ln;       // this lane's n-row within the tile

  const float* xb = x + ((size_t)b * Nn + (size_t)chunk * (TILES * RT)) * Dd;

  if (tid < Kk) { WsumL[tid] = 0.0f; tabL[tid] = tab[tid]; }
  __syncthreads();

  f32x4 acc[4][4];
  const f32x4 zero4 = {0.f, 0.f, 0.f, 0.f};
  #pragma unroll
  for (int mi = 0; mi < 4; ++mi)
    #pragma unroll
    for (int ni = 0; ni < 4; ++ni) acc[mi][ni] = zero4;

  const unsigned colb = (unsigned)row * 2u;  // this lane's n-column (bytes)
  // hoisted xT store addresses (rows g*8+i); +ks*8192 folds into the offset imm
  unsigned a_st[8];
  #pragma unroll
  for (int i = 0; i < 8; ++i) a_st[i] = lds_addr((unsigned)(g * 8 + i), colb);

  for (int t = 0; t < TILES; ++t) {
    // -------- Phase 1: S^T = mfma(c, x); each wave owns 16 rows x all 128 cw
    const float* xrow = xb + ((size_t)t * RT + row) * Dd;
    f32x4 s1[8];
    #pragma unroll
    for (int f = 0; f < 8; ++f) s1[f] = zero4;
    float x2p = 0.f;

    #pragma unroll
    for (int ks = 0; ks < 8; ++ks) {
      const int d0 = ks * 32 + g * 8;
      float4 u0 = *(const float4*)(xrow + d0);
      float4 u1 = *(const float4*)(xrow + d0 + 4);
      x2p += u0.x*u0.x + u0.y*u0.y + u0.z*u0.z + u0.w*u0.w
           + u1.x*u1.x + u1.y*u1.y + u1.z*u1.z + u1.w*u1.w;
      unsigned short q0 = f2bf(u0.x), q1 = f2bf(u0.y), q2 = f2bf(u0.z), q3 = f2bf(u0.w);
      unsigned short q4 = f2bf(u1.x), q5 = f2bf(u1.y), q6 = f2bf(u1.z), q7 = f2bf(u1.w);
      bf16x8 xv;
      xv[0] = (short)q0; xv[1] = (short)q1; xv[2] = (short)q2; xv[3] = (short)q3;
      xv[4] = (short)q4; xv[5] = (short)q5; xv[6] = (short)q6; xv[7] = (short)q7;
      // single x read feeds both MFMA operand and transposed LDS stage
      *(unsigned short*)(smem + a_st[0] + ks * 8192) = q0;
      *(unsigned short*)(smem + a_st[1] + ks * 8192) = q1;
      *(unsigned short*)(smem + a_st[2] + ks * 8192) = q2;
      *(unsigned short*)(smem + a_st[3] + ks * 8192) = q3;
      *(unsigned short*)(smem + a_st[4] + ks * 8192) = q4;
      *(unsigned short*)(smem + a_st[5] + ks * 8192) = q5;
      *(unsigned short*)(smem + a_st[6] + ks * 8192) = q6;
      *(unsigned short*)(smem + a_st[7] + ks * 8192) = q7;
      #pragma unroll
      for (int f = 0; f < 8; ++f) {
        bf16x8 a = *(const bf16x8*)(cbf + (f * 16 + ln) * Dd + d0);
        s1[f] = __builtin_amdgcn_mfma_f32_16x16x32_bf16(a, xv, s1[f], 0, 0, 0);
      }
    }

    // -------- softmax over K (lane-local: 32 values + 2 shuffles)
    x2p += __shfl_xor(x2p, 16); x2p += __shfl_xor(x2p, 32);
    const float hx2 = 0.5f * x2p;
    float ssum = 0.f;
    #pragma unroll
    for (int f = 0; f < 8; ++f) {
      #pragma unroll
      for (int r = 0; r < 4; ++r) {
        const float2 ab = tabL[f * 16 + g * 4 + r];     // (alpha, beta)
        const float ev = __expf(ab.x + ab.y * (hx2 - s1[f][r]));
        s1[f][r] = ev;
        ssum += ev;
      }
    }
    ssum += __shfl_xor(ssum, 16); ssum += __shfl_xor(ssum, 32);
    const float rinv = 1.0f / ssum;

    #pragma unroll
    for (int f = 0; f < 8; ++f) {
      #pragma unroll
      for (int r = 0; r < 4; ++r) {
        const int cwi = f * 16 + g * 4 + r;
        const float wv = s1[f][r] * rinv;
        *(unsigned short*)(Wb + lds_addr((unsigned)cwi, colb)) = f2bf(wv);
        float tsum = wv;                                // sum over the wave's 16 rows
        tsum += __shfl_xor(tsum, 1);
        tsum += __shfl_xor(tsum, 2);
        tsum += __shfl_xor(tsum, 4);
        tsum += __shfl_xor(tsum, 8);
        if (ln == 0) atomicAdd(&WsumL[cwi], tsum);
      }
    }
    __syncthreads();   // xT + W complete

    // -------- Phase 2: E(128x256) += W^T-frags x xT-frags, 2x4 wave grid
    #pragma unroll
    for (int ks2 = 0; ks2 < 4; ++ks2) {
      const unsigned nb = (unsigned)(ks2 * 32 + g * 8) * 2u;
      bf16x8 af[4], bg[4];
      #pragma unroll
      for (int mi = 0; mi < 4; ++mi)
        af[mi] = *(const bf16x8*)(Wb + lds_addr((unsigned)(wr * 64 + mi * 16 + ln), nb));
      #pragma unroll
      for (int ni = 0; ni < 4; ++ni)
        bg[ni] = *(const bf16x8*)(smem + lds_addr((unsigned)(wc * 64 + ni * 16 + ln), nb));
      #pragma unroll
      for (int mi = 0; mi < 4; ++mi)
        #pragma unroll
        for (int ni = 0; ni < 4; ++ni)
          acc[mi][ni] = __builtin_amdgcn_mfma_f32_16x16x32_bf16(af[mi], bg[ni], acc[mi][ni], 0, 0, 0);
    }
    __syncthreads();   // before next tile overwrites xT/W
  }

  // -------- epilogue: Epart[k,d] = acc - Wsum_chunk * c
  #pragma unroll
  for (int mi = 0; mi < 4; ++mi) {
    #pragma unroll
    for (int r = 0; r < 4; ++r) {
      const int cwi = wr * 64 + mi * 16 + g * 4 + r;
      const float wsv = WsumL[cwi];
      #pragma unroll
      for (int ni = 0; ni < 4; ++ni) {
        const int d = wc * 64 + ni * 16 + ln;
        const float v = acc[mi][ni][r] - wsv * cwf[cwi * Dd + d];
        if (PMODE == 0) {
          ((float*)Ep)[(size_t)blockIdx.x * (Kk * Dd) + cwi * Dd + d] = v;
        } else if (PMODE == 1) {
          ((unsigned short*)Ep)[(size_t)blockIdx.x * (Kk * Dd) + cwi * Dd + d] = f2bf(v);
        } else {
          atomicAdd(out + (size_t)b * (Kk * Dd) + cwi * Dd + d, v);
        }
      }
    }
  }
}

// LDS (97.5KB) already limits us to 1 block/CU = 2 waves/SIMD. Entitle the
// matching 256-VGPR budget explicitly: the default allocator heuristic picked
// 128 VGPRs and spilled acc[4][4] to scratch every tile (~134MB/dispatch each
// way of HBM traffic — rounds 1-6's wall).
#define ENC_ATTRS __attribute__((amdgpu_waves_per_eu(2, 2)))

__global__ __launch_bounds__(512) ENC_ATTRS void enc_main_f32(
    const float* __restrict__ x, const unsigned short* __restrict__ cbf,
    const float2* __restrict__ tab, const float* __restrict__ cwf,
    char* __restrict__ Ep, float* __restrict__ out) {
  enc_impl<0>(x, cbf, tab, cwf, Ep, out);
}
__global__ __launch_bounds__(512) ENC_ATTRS void enc_main_b16(
    const float* __restrict__ x, const unsigned short* __restrict__ cbf,
    const float2* __restrict__ tab, const float* __restrict__ cwf,
    char* __restrict__ Ep, float* __restrict__ out) {
  enc_impl<1>(x, cbf, tab, cwf, Ep, out);
}
__global__ __launch_bounds__(512) ENC_ATTRS void enc_main_atm(
    const float* __restrict__ x, const unsigned short* __restrict__ cbf,
    const float2* __restrict__ tab, const float* __restrict__ cwf,
    char* __restrict__ Ep, float* __restrict__ out) {
  enc_impl<2>(x, cbf, tab, cwf, nullptr, out);
}

// Each thread reduces 16 consecutive floats over 8 chunks: 32 independent
// 16B loads in flight per lane (in-flight-bytes bound, not BW bound).
__global__ __launch_bounds__(256, 1) void enc_reduce_f32(
    const float* __restrict__ Ep, float* __restrict__ out) {
  const size_t i = ((size_t)blockIdx.x * 256 + threadIdx.x) * 16;
  const int b   = (int)(i / (Kk * Dd));
  const int rem = (int)(i % (Kk * Dd));
  const float* p = Ep + (size_t)b * CHUNKS * (Kk * Dd) + rem;
  float sx[16];
  #pragma unroll
  for (int j = 0; j < 16; ++j) sx[j] = 0.f;
  #pragma unroll
  for (int c = 0; c < CHUNKS; ++c) {
    const float4* q = (const float4*)(p + (size_t)c * (Kk * Dd));
    float4 v0 = q[0], v1 = q[1], v2 = q[2], v3 = q[3];
    sx[0] += v0.x; sx[1] += v0.y; sx[2]  += v0.z; sx[3]  += v0.w;
    sx[4] += v1.x; sx[5] += v1.y; sx[6]  += v1.z; sx[7]  += v1.w;
    sx[8] += v2.x; sx[9] += v2.y; sx[10] += v2.z; sx[11] += v2.w;
    sx[12] += v3.x; sx[13] += v3.y; sx[14] += v3.z; sx[15] += v3.w;
  }
  float4* o = (float4*)(out + i);
  o[0] = make_float4(sx[0], sx[1], sx[2], sx[3]);
  o[1] = make_float4(sx[4], sx[5], sx[6], sx[7]);
  o[2] = make_float4(sx[8], sx[9], sx[10], sx[11]);
  o[3] = make_float4(sx[12], sx[13], sx[14], sx[15]);
}

__global__ void enc_reduce_bf16(const unsigned short* __restrict__ Ep, float* __restrict__ out) {
  const size_t i = ((size_t)blockIdx.x * 256 + threadIdx.x) * 4;
  const int b   = (int)(i / (Kk * Dd));
  const int rem = (int)(i % (Kk * Dd));
  const unsigned short* p = Ep + (size_t)b * CHUNKS * (Kk * Dd) + rem;
  float sx = 0.f, sy = 0.f, sz = 0.f, sw = 0.f;
  #pragma unroll
  for (int c = 0; c < CHUNKS; ++c) {
    ushort4 v = *(const ushort4*)(p + (size_t)c * (Kk * Dd));
    sx += bf2f(v.x); sy += bf2f(v.y); sz += bf2f(v.z); sw += bf2f(v.w);
  }
  float4 s = make_float4(sx, sy, sz, sw);
  *(float4*)(out + i) = s;
}

extern "C" void kernel_launch(void* const* d_in, const int* in_sizes, int n_in,
                              void* d_out, int out_size, void* d_ws, size_t ws_size,
                              hipStream_t stream) {
  const float* x  = (const float*)d_in[0];   // (32, 4096, 256)
  const float* cw = (const float*)d_in[1];   // (128, 256)
  const float* sc = (const float*)d_in[2];   // (128,)
  float* out = (float*)d_out;                // (32, 128, 256)

  unsigned short* cbf = (unsigned short*)d_ws;                    // 64KB bf16 codewords
  float2* tab = (float2*)((char*)d_ws + 65536);                   // 1KB (alpha, beta)
  char*   Ep  = (char*)d_ws + 66560;                              // chunk partials
  const size_t KD = (size_t)Kk * Dd;
  const size_t needF32 = 66560 + (size_t)32 * CHUNKS * KD * 4;    // ~33.6 MB
  const size_t needB16 = 66560 + (size_t)32 * CHUNKS * KD * 2;    // ~16.8 MB

  enc_prep<<<dim3(Kk), dim3(64), 0, stream>>>(cw, sc, cbf, tab);

  if (ws_size >= needF32) {
    enc_main_f32<<<dim3(256), dim3(512), 0, stream>>>(x, cbf, tab, cw, Ep, out);
    const int rgrid = (int)((32 * KD) / (256 * 16));              // 256 blocks
    enc_reduce_f32<<<dim3(rgrid), dim3(256), 0, stream>>>((const float*)Ep, out);
  } else if (ws_size >= needB16) {
    enc_main_b16<<<dim3(256), dim3(512), 0, stream>>>(x, cbf, tab, cw, Ep, out);
    const int rgrid = (int)((32 * KD) / (256 * 4));               // 1024 blocks
    enc_reduce_bf16<<<dim3(rgrid), dim3(256), 0, stream>>>((const unsigned short*)Ep, out);
  } else {
    hipMemsetAsync(d_out, 0, (size_t)out_size * sizeof(float), stream);
    enc_main_atm<<<dim3(256), dim3(512), 0, stream>>>(x, cbf, tab, cw, nullptr, out);
  }
}